// Round 2
// 100.249 us; speedup vs baseline: 1.0062x; 1.0062x over previous
//
#include <hip/hip_runtime.h>
#include <hip/hip_bf16.h>

typedef float f32x4 __attribute__((ext_vector_type(4)));
typedef short s16x8 __attribute__((ext_vector_type(8)));

#define NT 48
#define NE 48
#define NB 32
#define VS 512
#define NOUT (NT * NE * NB)
#define CX_OFF (3072 * 512)   // ws offset (floats) of Swb_q[4]

// ---------------- Kernel 1 ----------------
// C rows 0..1535    = exp(2*(ta+b1)) for m = t*32+b
// C rows 1536..3071 = exp(2*eb)      for m = 1536 + n*32+b
// Also: zero d_out; block 0 computes Swb_q[q] = b2/4 + sum_{h in quarter q} W2[h].
// Double-buffered LDS staging, one barrier per K-iteration.  (UNCHANGED)
__global__ __launch_bounds__(256) void k_gemm(
    const float* __restrict__ targets, const float* __restrict__ embeddings,
    const float* __restrict__ W1, const float* __restrict__ b1,
    const float* __restrict__ W2, const float* __restrict__ b2,
    float* __restrict__ C, float* __restrict__ out) {
  __shared__ short sa[2][64][40];
  __shared__ short sb[2][64][40];

  const int bid = blockIdx.x;
  const int tid = threadIdx.x;

  // zero the output (k_fuse accumulates atomically); 384*256 = 98304 >= 73728
  {
    int zi = bid * 256 + tid;
    if (zi < NOUT) out[zi] = 0.0f;
  }
  // per-quarter W2 sums (+ b2/4), block 0 wave 0
  if (bid == 0 && tid < 64) {
#pragma unroll
    for (int q = 0; q < 4; ++q) {
      float s = W2[q * 128 + tid] + W2[q * 128 + 64 + tid];
#pragma unroll
      for (int off = 32; off; off >>= 1) s += __shfl_xor(s, off, 64);
      if (tid == 0) C[CX_OFF + q] = 0.25f * b2[0] + s;
    }
  }

  const int mt = bid >> 3;            // 0..47
  const int ht = bid & 7;             // 0..7
  const int m0 = mt * 64, h0 = ht * 64;
  const bool is_ta = (m0 < 1536);
  const float* Abase = is_ta ? (targets + (size_t)m0 * VS)
                             : (embeddings + (size_t)(m0 - 1536) * VS);
  const float* Bbase = W1 + (size_t)h0 * 1024 + (is_ta ? 0 : 512);

  const int lane = tid & 63, w = tid >> 6;
  const int q = lane >> 4, i = lane & 15;

  const float* gsrc[4];
  int loff[4];
  bool isA[4];
#pragma unroll
  for (int r = 0; r < 4; ++r) {
    int f = r * 256 + tid;            // 0..1023
    int g = f & 511;
    int row = g >> 3;                 // 0..63
    int col4 = (g & 7) << 2;          // 0,4,..,28
    isA[r] = (f < 512);
    gsrc[r] = isA[r] ? (Abase + (size_t)row * VS + col4)
                     : (Bbase + (size_t)row * 1024 + col4);
    loff[r] = row * 40 + col4;
  }

  f32x4 acc[4] = {{0.f,0.f,0.f,0.f},{0.f,0.f,0.f,0.f},{0.f,0.f,0.f,0.f},{0.f,0.f,0.f,0.f}};

  f32x4 v[4];
#pragma unroll
  for (int r = 0; r < 4; ++r) v[r] = *(const f32x4*)(gsrc[r]);

  for (int kt = 0; kt < 16; ++kt) {
    const int p = kt & 1;
#pragma unroll
    for (int r = 0; r < 4; ++r) {
      union { __hip_bfloat162 h2; unsigned u; } c0, c1;
      c0.h2 = __float22bfloat162_rn(float2{v[r][0], v[r][1]});
      c1.h2 = __float22bfloat162_rn(float2{v[r][2], v[r][3]});
      uint2 o; o.x = c0.u; o.y = c1.u;
      short* base = isA[r] ? &sa[p][0][0] : &sb[p][0][0];
      *(uint2*)(base + loff[r]) = o;
    }
    __syncthreads();
    if (kt < 15) {
      const int k1 = (kt + 1) * 32;
#pragma unroll
      for (int r = 0; r < 4; ++r) v[r] = *(const f32x4*)(gsrc[r] + k1);
    }
    s16x8 av = *(const s16x8*)&sa[p][16 * w + i][q * 8];
#pragma unroll
    for (int c = 0; c < 4; ++c) {
      s16x8 bv = *(const s16x8*)&sb[p][c * 16 + i][q * 8];
      acc[c] = __builtin_amdgcn_mfma_f32_16x16x32_bf16(av, bv, acc[c], 0, 0, 0);
    }
  }

#pragma unroll
  for (int c = 0; c < 4; ++c) {
#pragma unroll
    for (int r = 0; r < 4; ++r) {
      int ml = 16 * w + q * 4 + r;
      int hl = c * 16 + i;
      int m = m0 + ml, h = h0 + hl;
      float vv = acc[c][r];
      if (is_ta) vv += b1[h];
      C[(size_t)m * VS + h] = __expf(vv + vv);
    }
  }
}

// ---------------- Kernel 2 (reworked) ----------------
// out[t,n,b] += Swb_q[hq] - 2 * sum_{h in quarter} W2[h] / (Et*En + 1)
// Grid: 3x3 tiles (16x16) x 4 h-quarters x 32 b = 1152 blocks, 256 threads.
// Transposed LDS (et_T[h][row], stride 20 floats: 16B-aligned, banks balanced),
// 4x4 per-thread blocking over 8 strided h (h = hsub + 16*s) -> 2.25 B LDS/rcp.
// Wave w owns Et row-quad w; lane>>4 = En col-quad; lane&15 = h phase.
#define ETS 20     // et_T/en_T row stride in floats
#define RPS 20     // red pos stride in floats
__global__ __launch_bounds__(256) void k_fuse(
    const float* __restrict__ C, const float* __restrict__ W2,
    float* __restrict__ out) {
  __shared__ float smem[128 * ETS * 2 + 128];   // etT | enT | w2c ; red overlays etT/enT
  float* etT = smem;                  // [h][row], h=0..127, row=0..15
  float* enT = smem + 128 * ETS;
  float* w2c = smem + 256 * ETS;
  float* red = smem;                  // [hsub][pos][slot], 16*16*RPS = 5120 floats

  const int bid = blockIdx.x;
  const int b  = bid & 31;
  const int r5 = bid >> 5;            // 0..35
  const int hq = r5 & 3;
  const int r2 = r5 >> 2;             // 0..8
  const int t0 = (r2 / 3) * 16, n0 = (r2 % 3) * 16;
  const int tid = threadIdx.x;

  // ---- stage Et/En transposed: per cell, 4 scalar loads (4 rows, same h) -> 1 b128 write
#pragma unroll
  for (int r = 0; r < 4; ++r) {
    int z = r * 256 + tid;            // 0..1023 cells
    int c2 = z & 511;
    int q  = c2 >> 7;                 // row-quad 0..3
    int h  = c2 & 127;                // lane-consecutive -> coalesced loads
    bool isE = (z >= 512);
    f32x4 v;
#pragma unroll
    for (int rr = 0; rr < 4; ++rr) {
      int row = q * 4 + rr;
      int m = isE ? (1536 + (n0 + row) * NB + b) : ((t0 + row) * NB + b);
      v[rr] = C[(size_t)m * VS + hq * 128 + h];
    }
    float* dst = (isE ? enT : etT) + h * ETS + q * 4;
    *(f32x4*)dst = v;
  }
  if (tid < 32) *(f32x4*)&w2c[tid * 4] = *(const f32x4*)&W2[hq * 128 + tid * 4];
  __syncthreads();

  const int w    = tid >> 6;          // wave = Et row-quad (pt)
  const int lane = tid & 63;
  const int pn   = lane >> 4;         // En col-quad
  const int hsub = lane & 15;         // h = hsub + 16*s  (20-stride -> banks balanced)

  float w2v[8];
#pragma unroll
  for (int s = 0; s < 8; ++s) w2v[s] = w2c[hsub + 16 * s];

  float acc[4][4] = {{0.f,0.f,0.f,0.f},{0.f,0.f,0.f,0.f},{0.f,0.f,0.f,0.f},{0.f,0.f,0.f,0.f}};
#pragma unroll
  for (int s = 0; s < 8; ++s) {
    int h = hsub + 16 * s;
    f32x4 et = *(const f32x4*)&etT[h * ETS + w * 4];    // 16 addrs, 4-way bcast
    f32x4 en = *(const f32x4*)&enT[h * ETS + pn * 4];   // 64 addrs, banks balanced
    float ww = w2v[s];
#pragma unroll
    for (int r = 0; r < 4; ++r)
#pragma unroll
      for (int u = 0; u < 4; ++u) {
        float rc = __builtin_amdgcn_rcpf(et[r] * en[u] + 1.0f);  // fma + rcp
        acc[r][u] += ww * rc;                                    // fmac
      }
  }
  __syncthreads();    // done reading etT/enT; red overlays them

  // write partials: red[hsub][pos= w*4+pn][slot-quad r^(hsub&3)] (XOR spreads banks)
  {
    float* dst = &red[((hsub * 16) + (w * 4 + pn)) * RPS];
#pragma unroll
    for (int r = 0; r < 4; ++r) {
      f32x4 v = { acc[r][0], acc[r][1], acc[r][2], acc[r][3] };
      *(f32x4*)&dst[(r ^ (hsub & 3)) * 4] = v;
    }
  }
  __syncthreads();

  // final: 64 threads, each 4 outputs (i, 4*jq+u); b128 reads across 16 h-phases
  if (tid < 64) {
    int i = tid >> 2, jq = tid & 3;
    int pos = (i >> 2) * 4 + jq;
    f32x4 ssum = {0.f, 0.f, 0.f, 0.f};
#pragma unroll
    for (int hs = 0; hs < 16; ++hs) {
      f32x4 v = *(const f32x4*)&red[(hs * 16 + pos) * RPS + (((i & 3) ^ (hs & 3)) * 4)];
      ssum += v;
    }
    float base = C[CX_OFF + hq];
#pragma unroll
    for (int u = 0; u < 4; ++u) {
      atomicAdd(&out[((size_t)(t0 + i) * NE + (n0 + jq * 4 + u)) * NB + b],
                base - 2.0f * ssum[u]);
    }
  }
}

extern "C" void kernel_launch(void* const* d_in, const int* in_sizes, int n_in,
                              void* d_out, int out_size, void* d_ws, size_t ws_size,
                              hipStream_t stream) {
  (void)in_sizes; (void)n_in; (void)out_size; (void)ws_size;
  const float* targets    = (const float*)d_in[0];
  const float* embeddings = (const float*)d_in[1];
  const float* W1         = (const float*)d_in[2];
  const float* b1         = (const float*)d_in[3];
  const float* W2         = (const float*)d_in[4];
  const float* b2         = (const float*)d_in[5];
  float* out = (float*)d_out;
  float* C   = (float*)d_ws;   // 3072*512 fp32 + 4 floats of Swb_q

  k_gemm<<<dim3(384), dim3(256), 0, stream>>>(targets, embeddings, W1, b1, W2, b2, C, out);
  k_fuse<<<dim3(1152), dim3(256), 0, stream>>>(C, W2, out);
}

// Round 3
// 100.226 us; speedup vs baseline: 1.0064x; 1.0002x over previous
//
#include <hip/hip_runtime.h>
#include <hip/hip_bf16.h>

typedef float f32x4 __attribute__((ext_vector_type(4)));
typedef short s16x8 __attribute__((ext_vector_type(8)));

#define NT 48
#define NE 48
#define NB 32
#define VS 512
#define NOUT (NT * NE * NB)
#define CX_OFF (3072 * 512)   // ws offset (floats) of Swb_q[4]

// ---------------- Kernel 1 ----------------
// C rows 0..1535    = exp(2*(ta+b1)) for m = t*32+b
// C rows 1536..3071 = exp(2*eb)      for m = 1536 + n*32+b
// Also: zero d_out; block 0 computes Swb_q[q] = b2/4 + sum_{h in quarter q} W2[h].
// XCD-banded job map: xcd=bid%8 owns mt band [6*xcd, 6*xcd+6) for ALL ht ->
// A-band (786KB) + full W1 (2MB) stay L2-resident per XCD; A re-reads become L2 hits.
__global__ __launch_bounds__(256) void k_gemm(
    const float* __restrict__ targets, const float* __restrict__ embeddings,
    const float* __restrict__ W1, const float* __restrict__ b1,
    const float* __restrict__ W2, const float* __restrict__ b2,
    float* __restrict__ C, float* __restrict__ out) {
  __shared__ short sa[2][64][40];
  __shared__ short sb[2][64][40];

  const int bid = blockIdx.x;
  const int tid = threadIdx.x;

  // zero the output (k_fuse accumulates atomically); 384*256 = 98304 >= 73728
  {
    int zi = bid * 256 + tid;
    if (zi < NOUT) out[zi] = 0.0f;
  }
  // per-quarter W2 sums (+ b2/4), block 0 wave 0
  if (bid == 0 && tid < 64) {
#pragma unroll
    for (int q = 0; q < 4; ++q) {
      float s = W2[q * 128 + tid] + W2[q * 128 + 64 + tid];
#pragma unroll
      for (int off = 32; off; off >>= 1) s += __shfl_xor(s, off, 64);
      if (tid == 0) C[CX_OFF + q] = 0.25f * b2[0] + s;
    }
  }

  // XCD-banded bijection: (xcd, j%6, j/6) <-> bid
  const int xcd = bid & 7;            // hw round-robin: xcd = bid % 8
  const int j   = bid >> 3;           // 0..47
  const int mt  = xcd * 6 + (j % 6);  // 0..47: contiguous band per XCD
  const int ht  = j / 6;              // 0..7
  const int m0 = mt * 64, h0 = ht * 64;
  const bool is_ta = (m0 < 1536);
  const float* Abase = is_ta ? (targets + (size_t)m0 * VS)
                             : (embeddings + (size_t)(m0 - 1536) * VS);
  const float* Bbase = W1 + (size_t)h0 * 1024 + (is_ta ? 0 : 512);

  const int lane = tid & 63, w = tid >> 6;
  const int q = lane >> 4, i = lane & 15;

  const float* gsrc[4];
  int loff[4];
  bool isA[4];
#pragma unroll
  for (int r = 0; r < 4; ++r) {
    int f = r * 256 + tid;            // 0..1023
    int g = f & 511;
    int row = g >> 3;                 // 0..63
    int col4 = (g & 7) << 2;          // 0,4,..,28
    isA[r] = (f < 512);
    gsrc[r] = isA[r] ? (Abase + (size_t)row * VS + col4)
                     : (Bbase + (size_t)row * 1024 + col4);
    loff[r] = row * 40 + col4;
  }

  f32x4 acc[4] = {{0.f,0.f,0.f,0.f},{0.f,0.f,0.f,0.f},{0.f,0.f,0.f,0.f},{0.f,0.f,0.f,0.f}};

  f32x4 v[4];
#pragma unroll
  for (int r = 0; r < 4; ++r) v[r] = *(const f32x4*)(gsrc[r]);

  for (int kt = 0; kt < 16; ++kt) {
    const int p = kt & 1;
#pragma unroll
    for (int r = 0; r < 4; ++r) {
      union { __hip_bfloat162 h2; unsigned u; } c0, c1;
      c0.h2 = __float22bfloat162_rn(float2{v[r][0], v[r][1]});
      c1.h2 = __float22bfloat162_rn(float2{v[r][2], v[r][3]});
      uint2 o; o.x = c0.u; o.y = c1.u;
      short* base = isA[r] ? &sa[p][0][0] : &sb[p][0][0];
      *(uint2*)(base + loff[r]) = o;
    }
    __syncthreads();
    if (kt < 15) {
      const int k1 = (kt + 1) * 32;
#pragma unroll
      for (int r = 0; r < 4; ++r) v[r] = *(const f32x4*)(gsrc[r] + k1);
    }
    s16x8 av = *(const s16x8*)&sa[p][16 * w + i][q * 8];
#pragma unroll
    for (int c = 0; c < 4; ++c) {
      s16x8 bv = *(const s16x8*)&sb[p][c * 16 + i][q * 8];
      acc[c] = __builtin_amdgcn_mfma_f32_16x16x32_bf16(av, bv, acc[c], 0, 0, 0);
    }
  }

#pragma unroll
  for (int c = 0; c < 4; ++c) {
#pragma unroll
    for (int r = 0; r < 4; ++r) {
      int ml = 16 * w + q * 4 + r;
      int hl = c * 16 + i;
      int m = m0 + ml, h = h0 + hl;
      float vv = acc[c][r];
      if (is_ta) vv += b1[h];
      C[(size_t)m * VS + h] = __expf(vv + vv);
    }
  }
}

// ---------------- Kernel 2 ----------------
// out[t,n,b] += Swb_q[hq] - 2 * sum_{h in quarter} W2[h] / (Et*En + 1)
// Grid: 1152 blocks, 256 threads. XCD map: hq = xcd>>1 (fixed per XCD pair) ->
// each XCD's 1.6MB C h-slice is L2-resident; 3x Et/En re-reads become L2 hits.
#define ETS 20     // et_T/en_T row stride in floats
#define RPS 20     // red pos stride in floats
__global__ __launch_bounds__(256) void k_fuse(
    const float* __restrict__ C, const float* __restrict__ W2,
    float* __restrict__ out) {
  __shared__ float smem[128 * ETS * 2 + 128];   // etT | enT | w2c ; red overlays etT/enT
  float* etT = smem;                  // [h][row], h=0..127, row=0..15
  float* enT = smem + 128 * ETS;
  float* w2c = smem + 256 * ETS;
  float* red = smem;                  // [hsub][pos][slot], 16*16*RPS = 5120 floats

  const int bid = blockIdx.x;
  // XCD bijection: hq = xcd>>1; jj = (bid>>3) + 144*(xcd&1) in 0..287
  const int xcd = bid & 7;
  const int hq  = xcd >> 1;           // 0..3, fixed per XCD pair
  const int jj  = (bid >> 3) + ((xcd & 1) * 144);  // 0..287
  const int b   = jj & 31;
  const int r2  = jj >> 5;            // 0..8
  const int t0 = (r2 / 3) * 16, n0 = (r2 % 3) * 16;
  const int tid = threadIdx.x;

  // ---- stage Et/En transposed: per cell, 4 scalar loads (4 rows, same h) -> 1 b128 write
#pragma unroll
  for (int r = 0; r < 4; ++r) {
    int z = r * 256 + tid;            // 0..1023 cells
    int c2 = z & 511;
    int q  = c2 >> 7;                 // row-quad 0..3
    int h  = c2 & 127;                // lane-consecutive -> coalesced loads
    bool isE = (z >= 512);
    f32x4 v;
#pragma unroll
    for (int rr = 0; rr < 4; ++rr) {
      int row = q * 4 + rr;
      int m = isE ? (1536 + (n0 + row) * NB + b) : ((t0 + row) * NB + b);
      v[rr] = C[(size_t)m * VS + hq * 128 + h];
    }
    float* dst = (isE ? enT : etT) + h * ETS + q * 4;
    *(f32x4*)dst = v;
  }
  if (tid < 32) *(f32x4*)&w2c[tid * 4] = *(const f32x4*)&W2[hq * 128 + tid * 4];
  __syncthreads();

  const int w    = tid >> 6;          // wave = Et row-quad (pt)
  const int lane = tid & 63;
  const int pn   = lane >> 4;         // En col-quad
  const int hsub = lane & 15;         // h = hsub + 16*s  (20-stride -> banks balanced)

  float w2v[8];
#pragma unroll
  for (int s = 0; s < 8; ++s) w2v[s] = w2c[hsub + 16 * s];

  float acc[4][4] = {{0.f,0.f,0.f,0.f},{0.f,0.f,0.f,0.f},{0.f,0.f,0.f,0.f},{0.f,0.f,0.f,0.f}};
#pragma unroll
  for (int s = 0; s < 8; ++s) {
    int h = hsub + 16 * s;
    f32x4 et = *(const f32x4*)&etT[h * ETS + w * 4];    // 16 addrs, 4-way bcast
    f32x4 en = *(const f32x4*)&enT[h * ETS + pn * 4];   // 64 addrs, banks balanced
    float ww = w2v[s];
#pragma unroll
    for (int r = 0; r < 4; ++r)
#pragma unroll
      for (int u = 0; u < 4; ++u) {
        float rc = __builtin_amdgcn_rcpf(et[r] * en[u] + 1.0f);  // fma + rcp
        acc[r][u] += ww * rc;                                    // fmac
      }
  }
  __syncthreads();    // done reading etT/enT; red overlays them

  // write partials: red[hsub][pos= w*4+pn][slot-quad r^(hsub&3)] (XOR spreads banks)
  {
    float* dst = &red[((hsub * 16) + (w * 4 + pn)) * RPS];
#pragma unroll
    for (int r = 0; r < 4; ++r) {
      f32x4 v = { acc[r][0], acc[r][1], acc[r][2], acc[r][3] };
      *(f32x4*)&dst[(r ^ (hsub & 3)) * 4] = v;
    }
  }
  __syncthreads();

  // final: 64 threads, each 4 outputs (i, 4*jq+u); b128 reads across 16 h-phases
  if (tid < 64) {
    int i = tid >> 2, jq = tid & 3;
    int pos = (i >> 2) * 4 + jq;
    f32x4 ssum = {0.f, 0.f, 0.f, 0.f};
#pragma unroll
    for (int hs = 0; hs < 16; ++hs) {
      f32x4 v = *(const f32x4*)&red[(hs * 16 + pos) * RPS + (((i & 3) ^ (hs & 3)) * 4)];
      ssum += v;
    }
    float base = C[CX_OFF + hq];
#pragma unroll
    for (int u = 0; u < 4; ++u) {
      atomicAdd(&out[((size_t)(t0 + i) * NE + (n0 + jq * 4 + u)) * NB + b],
                base - 2.0f * ssum[u]);
    }
  }
}

extern "C" void kernel_launch(void* const* d_in, const int* in_sizes, int n_in,
                              void* d_out, int out_size, void* d_ws, size_t ws_size,
                              hipStream_t stream) {
  (void)in_sizes; (void)n_in; (void)out_size; (void)ws_size;
  const float* targets    = (const float*)d_in[0];
  const float* embeddings = (const float*)d_in[1];
  const float* W1         = (const float*)d_in[2];
  const float* b1         = (const float*)d_in[3];
  const float* W2         = (const float*)d_in[4];
  const float* b2         = (const float*)d_in[5];
  float* out = (float*)d_out;
  float* C   = (float*)d_ws;   // 3072*512 fp32 + 4 floats of Swb_q

  k_gemm<<<dim3(384), dim3(256), 0, stream>>>(targets, embeddings, W1, b1, W2, b2, C, out);
  k_fuse<<<dim3(1152), dim3(256), 0, stream>>>(C, W2, out);
}